// Round 1
// baseline (1560.455 us; speedup 1.0000x reference)
//
#include <hip/hip_runtime.h>

#define U_NUM 50000
#define I_NUM 20000
#define F_DIM 64
#define N_EDGES 1000000
#define BATCH 131072

// One wave (64 lanes) per edge; lane = feature index.
// dst_emb[dst[e]][lane] += vals[e] * src_emb[src[e]][lane]
__global__ void spmm_scatter(const float* __restrict__ vals,
                             const int* __restrict__ src_idx,
                             const int* __restrict__ dst_idx,
                             const float* __restrict__ src_emb,
                             float* __restrict__ dst_emb)
{
    int t = blockIdx.x * blockDim.x + threadIdx.x;
    int e = t >> 6;
    int lane = t & 63;
    if (e >= N_EDGES) return;
    float v = vals[e];
    int s = src_idx[e];
    int d = dst_idx[e];
    float x = v * src_emb[(size_t)s * F_DIM + lane];
    atomicAdd(&dst_emb[(size_t)d * F_DIM + lane], x);
}

// y += s*x; optionally zero x afterwards (so the buffer is ready for reuse
// as an atomic-accumulation target without a separate memset pass).
__global__ void axpy_zero(float* __restrict__ y, float* __restrict__ x,
                          float s, int n, int zero_x)
{
    int i = blockIdx.x * blockDim.x + threadIdx.x;
    if (i < n) {
        y[i] += s * x[i];
        if (zero_x) x[i] = 0.f;
    }
}

// Wave per sample (lane = feature). Stable logaddexp; hierarchical reduce:
// wave shuffle -> block LDS -> one atomicAdd per block into *out.
__global__ void contrastive_loss(const float* __restrict__ old_emb,
                                 const float* __restrict__ gcn,
                                 const int* __restrict__ idx_u,
                                 const int* __restrict__ idx_i,
                                 const int* __restrict__ idx_j,
                                 const float* __restrict__ degree,
                                 float inv_num, float* __restrict__ out)
{
    __shared__ float warp_sums[4];
    int lane = threadIdx.x & 63;
    int wib  = threadIdx.x >> 6;
    int gw = (blockIdx.x * blockDim.x + threadIdx.x) >> 6;
    int nw = (gridDim.x * blockDim.x) >> 6;
    float acc = 0.f;
    for (int b = gw; b < BATCH; b += nw) {
        int u = idx_u[b], i = idx_i[b], j = idx_j[b];
        float uv = old_emb[(size_t)u * F_DIM + lane];
        float si = uv * gcn[(size_t)i * F_DIM + lane];
        float sj = uv * gcn[(size_t)j * F_DIM + lane];
        #pragma unroll
        for (int off = 32; off > 0; off >>= 1) {
            si += __shfl_down(si, off, 64);
            sj += __shfl_down(sj, off, 64);
        }
        if (lane == 0) {
            float m = fmaxf(si, sj);
            float lse = m + logf(expf(si - m) + expf(sj - m));
            acc += (si - lse) * degree[b];
        }
    }
    if (lane == 0) warp_sums[wib] = acc;
    __syncthreads();
    if (threadIdx.x == 0) {
        float s = warp_sums[0] + warp_sums[1] + warp_sums[2] + warp_sums[3];
        atomicAdd(out, -s * inv_num);
    }
}

extern "C" void kernel_launch(void* const* d_in, const int* in_sizes, int n_in,
                              void* d_out, int out_size, void* d_ws, size_t ws_size,
                              hipStream_t stream)
{
    const float* embed_user = (const float*)d_in[0];
    const float* embed_item = (const float*)d_in[1];
    const float* old_U      = (const float*)d_in[2];
    const float* old_I      = (const float*)d_in[3];
    const int*   erow       = (const int*)d_in[4];
    const int*   ecol       = (const int*)d_in[5];
    const float* ui_vals    = (const float*)d_in[6];
    const float* iu_vals    = (const float*)d_in[7];
    const int*   user       = (const int*)d_in[8];
    const int*   item_i     = (const int*)d_in[9];
    const int*   item_j     = (const int*)d_in[10];
    const float* degU       = (const float*)d_in[11];
    // d_in[12] = item_z_U (unused by reference)
    const int*   user_      = (const int*)d_in[13];
    const int*   item_i_    = (const int*)d_in[14];
    const int*   item_j_    = (const int*)d_in[15];
    const float* degI       = (const float*)d_in[16];
    // d_in[17] = item_z_I (unused by reference)

    const size_t UF = (size_t)U_NUM * F_DIM;   // 3,200,000 floats
    const size_t IF = (size_t)I_NUM * F_DIM;   // 1,280,000 floats
    float* ws    = (float*)d_ws;
    float* uA    = ws;              // u1, later u3
    float* uB    = uA + UF;         // u2
    float* iA    = uB + UF;         // i1, later i3
    float* iB    = iA + IF;         // i2
    float* gcn_u = iB + IF;
    float* gcn_i = gcn_u + UF;
    // total ws use: (3*UF + 3*IF)*4 = ~53.8 MB

    // Init: zero the 4 SpMM accumulators in one memset; gcn = level-0 embeds.
    hipMemsetAsync(uA, 0, (2 * UF + 2 * IF) * sizeof(float), stream);
    hipMemcpyAsync(gcn_u, embed_user, UF * sizeof(float),
                   hipMemcpyDeviceToDevice, stream);
    hipMemcpyAsync(gcn_i, embed_item, IF * sizeof(float),
                   hipMemcpyDeviceToDevice, stream);
    hipMemsetAsync(d_out, 0, sizeof(float), stream);

    dim3 blk(256);
    const int spmm_blocks = (int)(((long long)N_EDGES * 64 + 255) / 256); // 250,000
    const int ublk = (int)((UF + 255) / 256);
    const int iblk = (int)((IF + 255) / 256);

    // u1 = A @ i0     (dst=rows, src=cols)
    spmm_scatter<<<spmm_blocks, blk, 0, stream>>>(ui_vals, ecol, erow, embed_item, uA);
    // i1 = A^T @ u0   (dst=cols, src=rows)
    spmm_scatter<<<spmm_blocks, blk, 0, stream>>>(iu_vals, erow, ecol, embed_user, iA);
    // u2 = A @ i1
    spmm_scatter<<<spmm_blocks, blk, 0, stream>>>(ui_vals, ecol, erow, iA, uB);
    // i2 = A^T @ u1
    spmm_scatter<<<spmm_blocks, blk, 0, stream>>>(iu_vals, erow, ecol, uA, iB);

    // gcn += 0.5 * u1/i1, and zero uA/iA for reuse as u3/i3 accumulators
    axpy_zero<<<ublk, blk, 0, stream>>>(gcn_u, uA, 0.5f, (int)UF, 1);
    axpy_zero<<<iblk, blk, 0, stream>>>(gcn_i, iA, 0.5f, (int)IF, 1);

    // u3 = A @ i2 ; i3 = A^T @ u2
    spmm_scatter<<<spmm_blocks, blk, 0, stream>>>(ui_vals, ecol, erow, iB, uA);
    spmm_scatter<<<spmm_blocks, blk, 0, stream>>>(iu_vals, erow, ecol, uB, iA);

    // gcn += (1/3) * u2/i2
    axpy_zero<<<ublk, blk, 0, stream>>>(gcn_u, uB, 1.f / 3.f, (int)UF, 0);
    axpy_zero<<<iblk, blk, 0, stream>>>(gcn_i, iB, 1.f / 3.f, (int)IF, 0);
    // gcn += 0.25 * u3/i3
    axpy_zero<<<ublk, blk, 0, stream>>>(gcn_u, uA, 0.25f, (int)UF, 0);
    axpy_zero<<<iblk, blk, 0, stream>>>(gcn_i, iA, 0.25f, (int)IF, 0);

    // Contrastive losses accumulate into d_out[0]
    contrastive_loss<<<2048, blk, 0, stream>>>(old_U, gcn_u, user, item_i, item_j,
                                               degU, 1.f / U_NUM, (float*)d_out);
    contrastive_loss<<<2048, blk, 0, stream>>>(old_I, gcn_i, user_, item_i_, item_j_,
                                               degI, 1.f / I_NUM, (float*)d_out);
}

// Round 2
// 856.594 us; speedup vs baseline: 1.8217x; 1.8217x over previous
//
#include <hip/hip_runtime.h>

#define U_NUM 50000
#define I_NUM 20000
#define F_DIM 64
#define N_EDGES 1000000
#define BATCH 131072

// ---------------- CSR/CSC build ----------------

__global__ void count_edges(const int* __restrict__ rows, const int* __restrict__ cols,
                            int* __restrict__ cntU, int* __restrict__ cntI)
{
    int e = blockIdx.x * blockDim.x + threadIdx.x;
    if (e < N_EDGES) {
        atomicAdd(&cntU[rows[e]], 1);
        atomicAdd(&cntI[cols[e]], 1);
    }
}

// Single-block exclusive scan; each thread owns a contiguous chunk.
// Writes the same exclusive offsets to ptr (for the gather kernels) and
// cur (mutable cursors for the scatter pass).
__global__ void exscan_kernel(const int* __restrict__ cnt, int* __restrict__ ptr,
                              int* __restrict__ cur, int n)
{
    __shared__ int buf[1024];
    const int chunk = (n + 1023) / 1024;
    int start = threadIdx.x * chunk;
    int local = 0;
    for (int k = 0; k < chunk; k++) {
        int i = start + k;
        if (i < n) local += cnt[i];
    }
    buf[threadIdx.x] = local;
    __syncthreads();
    for (int off = 1; off < 1024; off <<= 1) {
        int t = (threadIdx.x >= (unsigned)off) ? buf[threadIdx.x - off] : 0;
        __syncthreads();
        buf[threadIdx.x] += t;
        __syncthreads();
    }
    int run = buf[threadIdx.x] - local;   // exclusive prefix of this chunk
    for (int k = 0; k < chunk; k++) {
        int i = start + k;
        if (i < n) {
            ptr[i] = run;
            cur[i] = run;
            run += cnt[i];
        }
    }
}

// Scatter edges into row-sorted (CSR, dst=user) and col-sorted (CSC, dst=item)
// arrays. Within-row order is nondeterministic — harmless for fp32 sums here.
__global__ void build_sorted(const int* __restrict__ rows, const int* __restrict__ cols,
                             const float* __restrict__ ui_vals, const float* __restrict__ iu_vals,
                             int* __restrict__ curU, int* __restrict__ curI,
                             int* __restrict__ srcU, float* __restrict__ valU,
                             int* __restrict__ srcI, float* __restrict__ valI)
{
    int e = blockIdx.x * blockDim.x + threadIdx.x;
    if (e >= N_EDGES) return;
    int r = rows[e], c = cols[e];
    int pU = atomicAdd(&curU[r], 1);
    srcU[pU] = c;
    valU[pU] = ui_vals[e];
    int pI = atomicAdd(&curI[c], 1);
    srcI[pI] = r;
    valI[pI] = iu_vals[e];
}

// ---------------- Gather SpMM ----------------
// One wave per destination row. Quarter-wave (16 lanes) per edge slot:
// lane = sub*16 + q, sub in 0..3 picks edge (k = sub + 4*iter), q picks the
// float4 feature block. Cross-sub reduction via shfl_xor(16,32); lanes 0..15
// store the 256B row with dwordx4. No atomics, overwrite semantics.
__global__ void spmm_gather(const int* __restrict__ ptr, const int* __restrict__ cnt,
                            const int* __restrict__ src_idx, const float* __restrict__ vals,
                            const float* __restrict__ src_emb, float* __restrict__ dst_emb,
                            int nrows)
{
    int wave = (blockIdx.x * blockDim.x + threadIdx.x) >> 6;
    if (wave >= nrows) return;
    int lane = threadIdx.x & 63;
    int sub  = lane >> 4;          // edge slot 0..3
    int q    = lane & 15;          // float4 block 0..15
    int begin = ptr[wave];
    int len   = cnt[wave];
    float4 acc = make_float4(0.f, 0.f, 0.f, 0.f);
    for (int k = sub; k < len; k += 4) {
        int e = begin + k;
        float v = vals[e];
        int s = src_idx[e];
        float4 x = ((const float4*)(src_emb + (size_t)s * F_DIM))[q];
        acc.x += v * x.x;
        acc.y += v * x.y;
        acc.z += v * x.z;
        acc.w += v * x.w;
    }
    acc.x += __shfl_xor(acc.x, 16, 64);
    acc.y += __shfl_xor(acc.y, 16, 64);
    acc.z += __shfl_xor(acc.z, 16, 64);
    acc.w += __shfl_xor(acc.w, 16, 64);
    acc.x += __shfl_xor(acc.x, 32, 64);
    acc.y += __shfl_xor(acc.y, 32, 64);
    acc.z += __shfl_xor(acc.z, 32, 64);
    acc.w += __shfl_xor(acc.w, 32, 64);
    if (sub == 0) {
        ((float4*)(dst_emb + (size_t)wave * F_DIM))[q] = acc;
    }
}

// ---------------- combine ----------------

__global__ void axpy1(float* __restrict__ y, const float* __restrict__ x, float a, int n)
{
    int i = blockIdx.x * blockDim.x + threadIdx.x;
    if (i < n) y[i] += a * x[i];
}

__global__ void axpy2(float* __restrict__ y, const float* __restrict__ x1, float a,
                      const float* __restrict__ x2, float b, int n)
{
    int i = blockIdx.x * blockDim.x + threadIdx.x;
    if (i < n) y[i] += a * x1[i] + b * x2[i];
}

// ---------------- contrastive loss ----------------

__global__ void contrastive_loss(const float* __restrict__ old_emb,
                                 const float* __restrict__ gcn,
                                 const int* __restrict__ idx_u,
                                 const int* __restrict__ idx_i,
                                 const int* __restrict__ idx_j,
                                 const float* __restrict__ degree,
                                 float inv_num, float* __restrict__ out)
{
    __shared__ float warp_sums[4];
    int lane = threadIdx.x & 63;
    int wib  = threadIdx.x >> 6;
    int gw = (blockIdx.x * blockDim.x + threadIdx.x) >> 6;
    int nw = (gridDim.x * blockDim.x) >> 6;
    float acc = 0.f;
    for (int b = gw; b < BATCH; b += nw) {
        int u = idx_u[b], i = idx_i[b], j = idx_j[b];
        float uv = old_emb[(size_t)u * F_DIM + lane];
        float si = uv * gcn[(size_t)i * F_DIM + lane];
        float sj = uv * gcn[(size_t)j * F_DIM + lane];
        #pragma unroll
        for (int off = 32; off > 0; off >>= 1) {
            si += __shfl_down(si, off, 64);
            sj += __shfl_down(sj, off, 64);
        }
        if (lane == 0) {
            float m = fmaxf(si, sj);
            float lse = m + logf(expf(si - m) + expf(sj - m));
            acc += (si - lse) * degree[b];
        }
    }
    if (lane == 0) warp_sums[wib] = acc;
    __syncthreads();
    if (threadIdx.x == 0) {
        float s = warp_sums[0] + warp_sums[1] + warp_sums[2] + warp_sums[3];
        atomicAdd(out, -s * inv_num);
    }
}

extern "C" void kernel_launch(void* const* d_in, const int* in_sizes, int n_in,
                              void* d_out, int out_size, void* d_ws, size_t ws_size,
                              hipStream_t stream)
{
    const float* embed_user = (const float*)d_in[0];
    const float* embed_item = (const float*)d_in[1];
    const float* old_U      = (const float*)d_in[2];
    const float* old_I      = (const float*)d_in[3];
    const int*   erow       = (const int*)d_in[4];
    const int*   ecol       = (const int*)d_in[5];
    const float* ui_vals    = (const float*)d_in[6];
    const float* iu_vals    = (const float*)d_in[7];
    const int*   user       = (const int*)d_in[8];
    const int*   item_i     = (const int*)d_in[9];
    const int*   item_j     = (const int*)d_in[10];
    const float* degU       = (const float*)d_in[11];
    const int*   user_      = (const int*)d_in[13];
    const int*   item_i_    = (const int*)d_in[14];
    const int*   item_j_    = (const int*)d_in[15];
    const float* degI       = (const float*)d_in[16];

    const size_t UF = (size_t)U_NUM * F_DIM;   // 3.2e6 floats
    const size_t IF = (size_t)I_NUM * F_DIM;   // 1.28e6 floats

    float* ws    = (float*)d_ws;
    float* uA    = ws;                  // u1, later u3
    float* uB    = uA + UF;             // u2
    float* iA    = uB + UF;             // i1, later i3
    float* iB    = iA + IF;             // i2
    float* gcn_u = iB + IF;
    float* gcn_i = gcn_u + UF;
    float* valU  = gcn_i + IF;          // sorted ui_vals (by row)
    float* valI  = valU + N_EDGES;      // sorted iu_vals (by col)
    int*   srcU  = (int*)(valI + N_EDGES);  // sorted cols (by row)
    int*   srcI  = srcU + N_EDGES;          // sorted rows (by col)
    int*   cntU  = srcI + N_EDGES;
    int*   ptrU  = cntU + U_NUM;
    int*   curU  = ptrU + U_NUM;
    int*   cntI  = curU + U_NUM;
    int*   ptrI  = cntI + I_NUM;
    int*   curI  = ptrI + I_NUM;
    // total ~70.6 MB

    dim3 blk(256);
    const int eblk = (N_EDGES + 255) / 256;        // 3907
    const int ublk = (int)((UF + 255) / 256);
    const int iblk = (int)((IF + 255) / 256);
    const int spmmU_blocks = U_NUM / 4;            // 12500 (wave per row)
    const int spmmI_blocks = I_NUM / 4;            // 5000

    // --- build CSR (U rows) + CSC (I cols) ---
    hipMemsetAsync(cntU, 0, (3 * U_NUM + 3 * I_NUM) * sizeof(int), stream);
    hipMemsetAsync(d_out, 0, sizeof(float), stream);
    count_edges<<<eblk, blk, 0, stream>>>(erow, ecol, cntU, cntI);
    exscan_kernel<<<1, 1024, 0, stream>>>(cntU, ptrU, curU, U_NUM);
    exscan_kernel<<<1, 1024, 0, stream>>>(cntI, ptrI, curI, I_NUM);
    build_sorted<<<eblk, blk, 0, stream>>>(erow, ecol, ui_vals, iu_vals,
                                           curU, curI, srcU, valU, srcI, valI);

    // --- gcn accumulators start at level-0 embeddings ---
    hipMemcpyAsync(gcn_u, embed_user, UF * sizeof(float), hipMemcpyDeviceToDevice, stream);
    hipMemcpyAsync(gcn_i, embed_item, IF * sizeof(float), hipMemcpyDeviceToDevice, stream);

    // --- propagation (gather SpMM, overwrite semantics) ---
    // u1 = A @ i0 ; i1 = A^T @ u0
    spmm_gather<<<spmmU_blocks, blk, 0, stream>>>(ptrU, cntU, srcU, valU, embed_item, uA, U_NUM);
    spmm_gather<<<spmmI_blocks, blk, 0, stream>>>(ptrI, cntI, srcI, valI, embed_user, iA, I_NUM);
    // u2 = A @ i1 ; i2 = A^T @ u1
    spmm_gather<<<spmmU_blocks, blk, 0, stream>>>(ptrU, cntU, srcU, valU, iA, uB, U_NUM);
    spmm_gather<<<spmmI_blocks, blk, 0, stream>>>(ptrI, cntI, srcI, valI, uA, iB, I_NUM);
    // gcn += 0.5 * level1
    axpy1<<<ublk, blk, 0, stream>>>(gcn_u, uA, 0.5f, (int)UF);
    axpy1<<<iblk, blk, 0, stream>>>(gcn_i, iA, 0.5f, (int)IF);
    // u3 = A @ i2 ; i3 = A^T @ u2   (reuse uA/iA)
    spmm_gather<<<spmmU_blocks, blk, 0, stream>>>(ptrU, cntU, srcU, valU, iB, uA, U_NUM);
    spmm_gather<<<spmmI_blocks, blk, 0, stream>>>(ptrI, cntI, srcI, valI, uB, iA, I_NUM);
    // gcn += (1/3)*level2 + 0.25*level3
    axpy2<<<ublk, blk, 0, stream>>>(gcn_u, uB, 1.f / 3.f, uA, 0.25f, (int)UF);
    axpy2<<<iblk, blk, 0, stream>>>(gcn_i, iB, 1.f / 3.f, iA, 0.25f, (int)IF);

    // --- losses ---
    contrastive_loss<<<2048, blk, 0, stream>>>(old_U, gcn_u, user, item_i, item_j,
                                               degU, 1.f / U_NUM, (float*)d_out);
    contrastive_loss<<<2048, blk, 0, stream>>>(old_I, gcn_i, user_, item_i_, item_j_,
                                               degI, 1.f / I_NUM, (float*)d_out);
}

// Round 3
// 761.787 us; speedup vs baseline: 2.0484x; 1.1245x over previous
//
#include <hip/hip_runtime.h>

#define U_NUM 50000
#define I_NUM 20000
#define F_DIM 64
#define N_EDGES 1000000
#define BATCH 131072

// ---------------- CSR/CSC build ----------------

__global__ void count_edges(const int* __restrict__ rows, const int* __restrict__ cols,
                            int* __restrict__ cntU, int* __restrict__ cntI)
{
    int e = blockIdx.x * blockDim.x + threadIdx.x;
    if (e < N_EDGES) {
        atomicAdd(&cntU[rows[e]], 1);
        atomicAdd(&cntI[cols[e]], 1);
    }
}

// Both exclusive scans in one launch: block 0 -> U table, block 1 -> I table.
// Each thread owns a contiguous chunk; LDS scan of per-thread sums.
__global__ void exscan_both(const int* __restrict__ cntU, int* __restrict__ ptrU, int* __restrict__ curU,
                            const int* __restrict__ cntI, int* __restrict__ ptrI, int* __restrict__ curI)
{
    const int* cnt;
    int *ptr, *cur, n;
    if (blockIdx.x == 0) { cnt = cntU; ptr = ptrU; cur = curU; n = U_NUM; }
    else                 { cnt = cntI; ptr = ptrI; cur = curI; n = I_NUM; }

    __shared__ int buf[1024];
    const int chunk = (n + 1023) / 1024;
    int start = threadIdx.x * chunk;
    int local = 0;
    for (int k = 0; k < chunk; k++) {
        int i = start + k;
        if (i < n) local += cnt[i];
    }
    buf[threadIdx.x] = local;
    __syncthreads();
    for (int off = 1; off < 1024; off <<= 1) {
        int t = (threadIdx.x >= (unsigned)off) ? buf[threadIdx.x - off] : 0;
        __syncthreads();
        buf[threadIdx.x] += t;
        __syncthreads();
    }
    int run = buf[threadIdx.x] - local;   // exclusive prefix of this chunk
    for (int k = 0; k < chunk; k++) {
        int i = start + k;
        if (i < n) {
            ptr[i] = run;
            cur[i] = run;
            run += cnt[i];
        }
    }
}

// Scatter edges into row-sorted (CSR, dst=user) and col-sorted (CSC, dst=item)
// arrays. (src,val) interleaved as int2 -> ONE 8B scattered store per edge per
// direction instead of two 4B stores to different lines (halves partial-line
// HBM write amplification). Within-row order nondeterministic (fp32 sum
// reorder only).
__global__ void build_sorted(const int* __restrict__ rows, const int* __restrict__ cols,
                             const float* __restrict__ ui_vals, const float* __restrict__ iu_vals,
                             int* __restrict__ curU, int* __restrict__ curI,
                             int2* __restrict__ edgesU, int2* __restrict__ edgesI)
{
    int e = blockIdx.x * blockDim.x + threadIdx.x;
    if (e >= N_EDGES) return;
    int r = rows[e], c = cols[e];
    int2 pu;
    pu.x = c;
    pu.y = __float_as_int(ui_vals[e]);
    edgesU[atomicAdd(&curU[r], 1)] = pu;
    int2 pi;
    pi.x = r;
    pi.y = __float_as_int(iu_vals[e]);
    edgesI[atomicAdd(&curI[c], 1)] = pi;
}

// ---------------- Gather SpMM with fused GCN epilogue ----------------
// One wave per destination row. Quarter-wave (16 lanes) per edge slot, k-loop
// unrolled x2 -> 8 row-gathers in flight per wave. After cross-sub reduction,
// lanes 0..15 hold the full row and run the epilogue:
//   MODE 0: dst = acc;  gcn = base + alpha*acc   (level 1, kills the memcpy)
//   MODE 1: dst = acc;  gcn += alpha*acc         (level 2)
//   MODE 2:             gcn += alpha*acc         (level 3, u3/i3 never stored)
template <int MODE>
__global__ void spmm_fused(const int* __restrict__ ptr, const int* __restrict__ cnt,
                           const int2* __restrict__ edges,
                           const float* __restrict__ src_emb,
                           float* __restrict__ dst_emb,
                           const float* __restrict__ base,
                           float* __restrict__ gcn,
                           float alpha, int nrows)
{
    int wave = (blockIdx.x * blockDim.x + threadIdx.x) >> 6;
    if (wave >= nrows) return;
    int lane = threadIdx.x & 63;
    int sub  = lane >> 4;          // edge slot 0..3
    int q    = lane & 15;          // float4 block 0..15
    int begin = ptr[wave];
    int len   = cnt[wave];

    float4 a0 = make_float4(0.f, 0.f, 0.f, 0.f);
    float4 a1 = make_float4(0.f, 0.f, 0.f, 0.f);
    int k = sub;
    for (; k + 4 < len; k += 8) {
        int2 e0 = edges[begin + k];
        int2 e1 = edges[begin + k + 4];
        float4 x0 = ((const float4*)(src_emb + (size_t)e0.x * F_DIM))[q];
        float4 x1 = ((const float4*)(src_emb + (size_t)e1.x * F_DIM))[q];
        float v0 = __int_as_float(e0.y);
        float v1 = __int_as_float(e1.y);
        a0.x += v0 * x0.x; a0.y += v0 * x0.y; a0.z += v0 * x0.z; a0.w += v0 * x0.w;
        a1.x += v1 * x1.x; a1.y += v1 * x1.y; a1.z += v1 * x1.z; a1.w += v1 * x1.w;
    }
    if (k < len) {
        int2 e0 = edges[begin + k];
        float4 x0 = ((const float4*)(src_emb + (size_t)e0.x * F_DIM))[q];
        float v0 = __int_as_float(e0.y);
        a0.x += v0 * x0.x; a0.y += v0 * x0.y; a0.z += v0 * x0.z; a0.w += v0 * x0.w;
    }
    float4 acc;
    acc.x = a0.x + a1.x;
    acc.y = a0.y + a1.y;
    acc.z = a0.z + a1.z;
    acc.w = a0.w + a1.w;

    acc.x += __shfl_xor(acc.x, 16, 64);
    acc.y += __shfl_xor(acc.y, 16, 64);
    acc.z += __shfl_xor(acc.z, 16, 64);
    acc.w += __shfl_xor(acc.w, 16, 64);
    acc.x += __shfl_xor(acc.x, 32, 64);
    acc.y += __shfl_xor(acc.y, 32, 64);
    acc.z += __shfl_xor(acc.z, 32, 64);
    acc.w += __shfl_xor(acc.w, 32, 64);

    if (sub == 0) {
        size_t off = (size_t)wave * F_DIM;
        if (MODE < 2) ((float4*)(dst_emb + off))[q] = acc;
        float4 g;
        if (MODE == 0) g = ((const float4*)(base + off))[q];
        else           g = ((const float4*)(gcn + off))[q];
        g.x += alpha * acc.x;
        g.y += alpha * acc.y;
        g.z += alpha * acc.z;
        g.w += alpha * acc.w;
        ((float4*)(gcn + off))[q] = g;
    }
}

// ---------------- fused contrastive loss (both halves) ----------------
// First gridDim/2 blocks -> U loss, rest -> I loss. One atomic per block.
__global__ void contrastive_both(const float* __restrict__ oldU, const float* __restrict__ gcnU,
                                 const int* __restrict__ userU, const int* __restrict__ iiU,
                                 const int* __restrict__ ijU, const float* __restrict__ degU,
                                 const float* __restrict__ oldI, const float* __restrict__ gcnI,
                                 const int* __restrict__ userI, const int* __restrict__ iiI,
                                 const int* __restrict__ ijI, const float* __restrict__ degI,
                                 float* __restrict__ out)
{
    __shared__ float warp_sums[4];
    int half = gridDim.x >> 1;
    bool second = blockIdx.x >= half;
    const float* old_emb = second ? oldI : oldU;
    const float* gcn     = second ? gcnI : gcnU;
    const int* idx_u     = second ? userI : userU;
    const int* idx_i     = second ? iiI : iiU;
    const int* idx_j     = second ? ijI : ijU;
    const float* degree  = second ? degI : degU;
    float inv_num        = second ? (1.f / I_NUM) : (1.f / U_NUM);
    int bid = second ? (blockIdx.x - half) : blockIdx.x;

    int lane = threadIdx.x & 63;
    int wib  = threadIdx.x >> 6;
    int gw = (bid * blockDim.x + threadIdx.x) >> 6;
    int nw = (half * blockDim.x) >> 6;
    float acc = 0.f;
    for (int b = gw; b < BATCH; b += nw) {
        int u = idx_u[b], i = idx_i[b], j = idx_j[b];
        float uv = old_emb[(size_t)u * F_DIM + lane];
        float si = uv * gcn[(size_t)i * F_DIM + lane];
        float sj = uv * gcn[(size_t)j * F_DIM + lane];
        #pragma unroll
        for (int off = 32; off > 0; off >>= 1) {
            si += __shfl_down(si, off, 64);
            sj += __shfl_down(sj, off, 64);
        }
        if (lane == 0) {
            float m = fmaxf(si, sj);
            float lse = m + logf(expf(si - m) + expf(sj - m));
            acc += (si - lse) * degree[b];
        }
    }
    if (lane == 0) warp_sums[wib] = acc;
    __syncthreads();
    if (threadIdx.x == 0) {
        float s = warp_sums[0] + warp_sums[1] + warp_sums[2] + warp_sums[3];
        atomicAdd(out, -s * inv_num);
    }
}

extern "C" void kernel_launch(void* const* d_in, const int* in_sizes, int n_in,
                              void* d_out, int out_size, void* d_ws, size_t ws_size,
                              hipStream_t stream)
{
    const float* embed_user = (const float*)d_in[0];
    const float* embed_item = (const float*)d_in[1];
    const float* old_U      = (const float*)d_in[2];
    const float* old_I      = (const float*)d_in[3];
    const int*   erow       = (const int*)d_in[4];
    const int*   ecol       = (const int*)d_in[5];
    const float* ui_vals    = (const float*)d_in[6];
    const float* iu_vals    = (const float*)d_in[7];
    const int*   user       = (const int*)d_in[8];
    const int*   item_i     = (const int*)d_in[9];
    const int*   item_j     = (const int*)d_in[10];
    const float* degU       = (const float*)d_in[11];
    const int*   user_      = (const int*)d_in[13];
    const int*   item_i_    = (const int*)d_in[14];
    const int*   item_j_    = (const int*)d_in[15];
    const float* degI       = (const float*)d_in[16];

    const size_t UF = (size_t)U_NUM * F_DIM;   // 3.2e6 floats
    const size_t IF = (size_t)I_NUM * F_DIM;   // 1.28e6 floats

    // Layout: int2 edge arrays first (8B alignment), then float tables, then aux.
    int2*  edgesU = (int2*)d_ws;                     // 8 MB
    int2*  edgesI = edgesU + N_EDGES;                // 8 MB
    float* uA     = (float*)(edgesI + N_EDGES);      // u1
    float* uB     = uA + UF;                         // u2
    float* iA     = uB + UF;                         // i1
    float* iB     = iA + IF;                         // i2
    float* gcn_u  = iB + IF;
    float* gcn_i  = gcn_u + UF;
    int*   cntU   = (int*)(gcn_i + IF);
    int*   ptrU   = cntU + U_NUM;
    int*   curU   = ptrU + U_NUM;
    int*   cntI   = curU + U_NUM;
    int*   ptrI   = cntI + I_NUM;
    int*   curI   = ptrI + I_NUM;
    // total ~70.6 MB

    dim3 blk(256);
    const int eblk = (N_EDGES + 255) / 256;        // 3907
    const int spmmU_blocks = U_NUM / 4;            // 12500 (wave per row)
    const int spmmI_blocks = I_NUM / 4;            // 5000

    // --- build CSR (U rows) + CSC (I cols) ---
    hipMemsetAsync(cntU, 0, (3 * U_NUM + 3 * I_NUM) * sizeof(int), stream);
    hipMemsetAsync(d_out, 0, sizeof(float), stream);
    count_edges<<<eblk, blk, 0, stream>>>(erow, ecol, cntU, cntI);
    exscan_both<<<2, 1024, 0, stream>>>(cntU, ptrU, curU, cntI, ptrI, curI);
    build_sorted<<<eblk, blk, 0, stream>>>(erow, ecol, ui_vals, iu_vals,
                                           curU, curI, edgesU, edgesI);

    // --- propagation with fused GCN combine ---
    // L1: u1 = A@i0, gcn_u = embed_user + 0.5*u1 ; i1 = At@u0, gcn_i = embed_item + 0.5*i1
    spmm_fused<0><<<spmmU_blocks, blk, 0, stream>>>(ptrU, cntU, edgesU, embed_item,
                                                    uA, embed_user, gcn_u, 0.5f, U_NUM);
    spmm_fused<0><<<spmmI_blocks, blk, 0, stream>>>(ptrI, cntI, edgesI, embed_user,
                                                    iA, embed_item, gcn_i, 0.5f, I_NUM);
    // L2: u2 = A@i1, gcn_u += (1/3)*u2 ; i2 = At@u1, gcn_i += (1/3)*i2
    spmm_fused<1><<<spmmU_blocks, blk, 0, stream>>>(ptrU, cntU, edgesU, iA,
                                                    uB, nullptr, gcn_u, 1.f / 3.f, U_NUM);
    spmm_fused<1><<<spmmI_blocks, blk, 0, stream>>>(ptrI, cntI, edgesI, uA,
                                                    iB, nullptr, gcn_i, 1.f / 3.f, I_NUM);
    // L3: gcn_u += 0.25*(A@i2) ; gcn_i += 0.25*(At@u2)   (u3/i3 never stored)
    spmm_fused<2><<<spmmU_blocks, blk, 0, stream>>>(ptrU, cntU, edgesU, iB,
                                                    nullptr, nullptr, gcn_u, 0.25f, U_NUM);
    spmm_fused<2><<<spmmI_blocks, blk, 0, stream>>>(ptrI, cntI, edgesI, uB,
                                                    nullptr, nullptr, gcn_i, 0.25f, I_NUM);

    // --- both losses in one kernel ---
    contrastive_both<<<4096, blk, 0, stream>>>(old_U, gcn_u, user, item_i, item_j, degU,
                                               old_I, gcn_i, user_, item_i_, item_j_, degI,
                                               (float*)d_out);
}